// Round 1
// 447.692 us; speedup vs baseline: 5.5491x; 5.5491x over previous
//
#include <hip/hip_runtime.h>
#include <hip/hip_bf16.h>

#define NB_  4096   // B_ = B*NW windows
#define NG_  49
#define NC_  128
#define NH_  4
#define DH_  32
#define NN_  50     // NG+1
#define NIMG 64
#define NT_  3136
#define SCALE_ 0.17677669529663687f

// workspace layout (u16 units)
#define WT_LO_OFF 49152      // low-order (residual) weight frags
#define BM_OFF    98304      // combined bias+mask table [widx][h][64][64] bf16

typedef unsigned short u16;
typedef unsigned int   u32;
typedef __attribute__((ext_vector_type(8))) short bf16x8;   // 8 bf16 (4 VGPRs)
typedef __attribute__((ext_vector_type(4))) float f32x4;    // MFMA acc

__device__ __forceinline__ float b2f(u16 u) {
    union { u32 i; float f; } v; v.i = ((u32)u) << 16; return v.f;
}
__device__ __forceinline__ u16 f2b(float f) {
    union { float f; u32 i; } v; v.f = f;
    u32 x = v.i;
    return (u16)((x + 0x7fffu + ((x >> 16) & 1u)) >> 16);
}
__device__ __forceinline__ u32 pk2(float a, float b) {   // 2xf32 -> packed bf16x2 (RNE)
    union { __hip_bfloat162 h2; u32 u; } v;
    v.h2 = __float22bfloat162_rn(make_float2(a, b));
    return v.u;
}

// ---------------- pre-pass: weight frags (hi/lo) + combined bias table ----------------
extern "C" __global__ __launch_bounds__(256)
void prep_kernel(const float* __restrict__ Wq, const float* __restrict__ Wkv,
                 const float* __restrict__ btab, const int* __restrict__ ridx,
                 const float* __restrict__ mask, u16* __restrict__ ws)
{
    const int t = threadIdx.x, b = blockIdx.x;
    if (b < 24) {
        // weight fragment packing: tile tn=b (16 cols of [q|k|v] 384), kt = K-tile
        const int tn = b, kt = t >> 6, lane = t & 63;
        const int j  = tn * 16 + (lane & 15);          // output col 0..383
        const int k0 = kt * 32 + (lane >> 4) * 8;      // K base for this lane
        u32 hi[4], lo[4];
        #pragma unroll
        for (int p = 0; p < 4; ++p) {
            const int k = k0 + 2 * p;
            float w0 = (j < 128) ? Wq[(size_t)k * 128 + j]       : Wkv[(size_t)k * 256 + (j - 128)];
            float w1 = (j < 128) ? Wq[(size_t)(k + 1) * 128 + j] : Wkv[(size_t)(k + 1) * 256 + (j - 128)];
            u16 h0 = f2b(w0), h1 = f2b(w1);
            hi[p] = (u32)h0 | ((u32)h1 << 16);
            lo[p] = (u32)f2b(w0 - b2f(h0)) | ((u32)f2b(w1 - b2f(h1)) << 16);
        }
        const size_t fo = ((size_t)(tn * 4 + kt) * 64 + lane) * 8;
        *(uint4*)(ws + fo)             = make_uint4(hi[0], hi[1], hi[2], hi[3]);
        *(uint4*)(ws + WT_LO_OFF + fo) = make_uint4(lo[0], lo[1], lo[2], lo[3]);
    } else {
        // combined bias+mask: bm[widx][h][n(64)][m(64)], pads = -1e30
        const int idx = (b - 24) * 256 + t;            // 0..262143, 4 m's each
        const int mq  = idx & 15;
        const int n   = (idx >> 4) & 63;
        const int h   = (idx >> 10) & 3;
        const int wx  = idx >> 12;
        u16 vv[4];
        #pragma unroll
        for (int e = 0; e < 4; ++e) {
            const int m = mq * 4 + e;
            float val = -1e30f;
            if (n < NG_ && m < NN_)
                val = btab[ridx[n * NN_ + m] * NH_ + h] + mask[((size_t)wx * NG_ + n) * NN_ + m];
            vv[e] = f2b(val);
        }
        u32* dst = (u32*)(ws + BM_OFF + ((size_t)((wx * 4 + h) * 64 + n) * 16 + mq) * 4);
        dst[0] = (u32)vv[0] | ((u32)vv[1] << 16);
        dst[1] = (u32)vv[2] | ((u32)vv[3] << 16);
    }
}

// ---------------- main kernel ----------------
struct WinShared {              // all bf16, XOR-swizzled: u16 idx ^= (row&7)<<3
    u16 xc[64][128];            // x_c staged (rows 50..63 zero)
    u16 q [64][128];            // scaled q
    u16 k [64][128];
    u16 vT[128][64];            // v transposed: vT[col][krow]
};                              // 65536 B exactly
struct GlobShared {
    float qa[NH_][DH_];
    float xavgS[NC_];
    float u[NH_][NC_];
    float cst[NH_];
    float smax[NH_];
    float ssum[NH_];
    float red[256];
    float wpart[2][NH_][NC_];
    float s[NT_][NH_];
};
union SMem { WinShared w; GlobShared g; };

extern "C" __global__ __launch_bounds__(256, 2)
void wa2_kernel(const float* __restrict__ x, const float* __restrict__ xtotal,
                const float* __restrict__ xavg,
                const float* __restrict__ Wq, const float* __restrict__ bq,
                const float* __restrict__ Wkv, const float* __restrict__ bkv,
                float* __restrict__ out, const u16* __restrict__ ws)
{
    __shared__ SMem sm;
    const int t = threadIdx.x;
    const int blk = blockIdx.x;

    if (blk >= NIMG) {
        // ======================= window path (MFMA) =======================
        WinShared& S = sm.w;
        const int wb   = blk - NIMG;
        const int img  = wb >> 6;
        const int widx = wb & 63;
        const int lane = t & 63, wv = t >> 6;
        const int l15  = lane & 15, g = lane >> 4;

        // ---- stage x_c as bf16 (swizzled) ----
        {
            const float2* xr = (const float2*)(x + (size_t)wb * (NG_ * NC_));
            for (int i = t; i < NG_ * 64; i += 256) {
                const int row = i >> 6, cp = i & 63;
                float2 xv = xr[i];
                *(u32*)&S.xc[row][(2 * cp) ^ ((row & 7) << 3)] = pk2(xv.x, xv.y);
            }
            if (t < 64) {
                float2 av = ((const float2*)(xavg + (size_t)img * NC_))[t];
                *(u32*)&S.xc[49][(2 * t) ^ (1 << 3)] = pk2(av.x, av.y);
            }
            for (int i = t; i < 14 * 64; i += 256) {
                const int row = 50 + (i >> 6), cp = i & 63;
                *(u32*)&S.xc[row][(2 * cp) ^ ((row & 7) << 3)] = 0u;
            }
        }
        __syncthreads();

        // ---- projection: [64x128] @ [128x384] (hi+lo double-bf16 weights) ----
        {
            const int sw = (l15 & 7) << 3;
            bf16x8 a[4][4];                     // [tm][kt] A-frags from xc
            #pragma unroll
            for (int tm = 0; tm < 4; ++tm)
                #pragma unroll
                for (int kt = 0; kt < 4; ++kt)
                    a[tm][kt] = *(const bf16x8*)&S.xc[16 * tm + l15][(32 * kt + 8 * g) ^ sw];

            for (int i = 0; i < 6; ++i) {
                const int tn = 6 * wv + i;      // this wave's global col-tile
                const int jc = tn * 16 + l15;   // output col 0..383
                f32x4 z = {0.f, 0.f, 0.f, 0.f};
                f32x4 acc[4] = {z, z, z, z};
                #pragma unroll
                for (int kt = 0; kt < 4; ++kt) {
                    const size_t fo = ((size_t)(tn * 4 + kt) * 64 + lane) * 8;
                    bf16x8 bh = *(const bf16x8*)(ws + fo);
                    bf16x8 bl = *(const bf16x8*)(ws + WT_LO_OFF + fo);
                    #pragma unroll
                    for (int tm = 0; tm < 4; ++tm) {
                        acc[tm] = __builtin_amdgcn_mfma_f32_16x16x32_bf16(a[tm][kt], bh, acc[tm], 0, 0, 0);
                        acc[tm] = __builtin_amdgcn_mfma_f32_16x16x32_bf16(a[tm][kt], bl, acc[tm], 0, 0, 0);
                    }
                }
                const float bias = (jc < 128) ? bq[jc] : bkv[jc - 128];
                #pragma unroll
                for (int tm = 0; tm < 4; ++tm) {
                    #pragma unroll
                    for (int r = 0; r < 4; ++r) {
                        const int row = 16 * tm + 4 * g + r;
                        const float vvl = acc[tm][r] + bias;
                        if (jc < 128) {
                            S.q[row][jc ^ ((row & 7) << 3)] = f2b(vvl * SCALE_);
                        } else if (jc < 256) {
                            S.k[row][(jc - 128) ^ ((row & 7) << 3)] = f2b(vvl);
                        } else {
                            const int c = jc - 256;
                            S.vT[c][row ^ ((c & 7) << 3)] = f2b(vvl);
                        }
                    }
                }
            }
        }
        __syncthreads();

        // ---- attention: wave = head; swapped QK^T, in-register softmax ----
        {
            const int h = wv;
            const int sw = (l15 & 7) << 3;
            bf16x8 ka[4], qb[4];
            #pragma unroll
            for (int tk = 0; tk < 4; ++tk)
                ka[tk] = *(const bf16x8*)&S.k[16 * tk + l15][(32 * h + 8 * g) ^ sw];
            #pragma unroll
            for (int tq = 0; tq < 4; ++tq)
                qb[tq] = *(const bf16x8*)&S.q[16 * tq + l15][(32 * h + 8 * g) ^ sw];

            // S^T = K @ Q^T : lane holds kcol = 16tk+4g+r, qrow = 16tq+l15
            f32x4 s[4][4];   // [tk][tq]
            #pragma unroll
            for (int tk = 0; tk < 4; ++tk)
                #pragma unroll
                for (int tq = 0; tq < 4; ++tq) {
                    f32x4 z = {0.f, 0.f, 0.f, 0.f};
                    s[tk][tq] = __builtin_amdgcn_mfma_f32_16x16x32_bf16(ka[tk], qb[tq], z, 0, 0, 0);
                }

            // + bias + mask (pads carry -1e30)
            const u16* bmb = ws + BM_OFF + (size_t)((widx * 4 + h) * 64) * 64;
            #pragma unroll
            for (int tq = 0; tq < 4; ++tq) {
                const int qr = 16 * tq + l15;
                #pragma unroll
                for (int tk = 0; tk < 4; ++tk) {
                    uint2 bm = *(const uint2*)(bmb + qr * 64 + 16 * tk + 4 * g);
                    s[tk][tq][0] += b2f((u16)bm.x);
                    s[tk][tq][1] += b2f((u16)(bm.x >> 16));
                    s[tk][tq][2] += b2f((u16)bm.y);
                    s[tk][tq][3] += b2f((u16)(bm.y >> 16));
                }
            }

            // softmax over kcol per qrow: 16 in-lane + 2 shfl_xor (g-groups)
            float inv[4];
            #pragma unroll
            for (int tq = 0; tq < 4; ++tq) {
                float m = s[0][tq][0];
                #pragma unroll
                for (int tk = 0; tk < 4; ++tk)
                    #pragma unroll
                    for (int r = 0; r < 4; ++r) m = fmaxf(m, s[tk][tq][r]);
                m = fmaxf(m, __shfl_xor(m, 16));
                m = fmaxf(m, __shfl_xor(m, 32));
                float sum = 0.f;
                #pragma unroll
                for (int tk = 0; tk < 4; ++tk)
                    #pragma unroll
                    for (int r = 0; r < 4; ++r) {
                        float e = __expf(s[tk][tq][r] - m);
                        s[tk][tq][r] = e;
                        sum += e;
                    }
                sum += __shfl_xor(sum, 16);
                sum += __shfl_xor(sum, 32);
                inv[tq] = 1.f / sum;
            }

            // pack P in-register into AV A-frags; k-perm mirrored on V-frag reads
            bf16x8 pa[4][2];   // [tq][kt]; slot (g,e) <-> kcol 32kt+16(e>>2)+4g+(e&3)
            #pragma unroll
            for (int tq = 0; tq < 4; ++tq) {
                const float iv = inv[tq];
                #pragma unroll
                for (int kt = 0; kt < 2; ++kt) {
                    union { u32 u[4]; bf16x8 v; } P;
                    P.u[0] = pk2(s[2 * kt][tq][0] * iv, s[2 * kt][tq][1] * iv);
                    P.u[1] = pk2(s[2 * kt][tq][2] * iv, s[2 * kt][tq][3] * iv);
                    P.u[2] = pk2(s[2 * kt + 1][tq][0] * iv, s[2 * kt + 1][tq][1] * iv);
                    P.u[3] = pk2(s[2 * kt + 1][tq][2] * iv, s[2 * kt + 1][tq][3] * iv);
                    pa[tq][kt] = P.v;
                }
            }
            bf16x8 vb[2][2];   // [kt][tn] V B-frags, same k-perm
            #pragma unroll
            for (int tn = 0; tn < 2; ++tn) {
                const int c = 32 * h + 16 * tn + l15;
                const int swv = (c & 7) << 3;
                #pragma unroll
                for (int kt = 0; kt < 2; ++kt) {
                    union { uint2 u2[2]; bf16x8 v; } B;
                    B.u2[0] = *(const uint2*)&S.vT[c][(32 * kt + 4 * g) ^ swv];
                    B.u2[1] = *(const uint2*)&S.vT[c][(32 * kt + 16 + 4 * g) ^ swv];
                    vb[kt][tn] = B.v;
                }
            }
            #pragma unroll
            for (int tq = 0; tq < 4; ++tq)
                #pragma unroll
                for (int tn = 0; tn < 2; ++tn) {
                    f32x4 acc = {0.f, 0.f, 0.f, 0.f};
                    acc = __builtin_amdgcn_mfma_f32_16x16x32_bf16(pa[tq][0], vb[0][tn], acc, 0, 0, 0);
                    acc = __builtin_amdgcn_mfma_f32_16x16x32_bf16(pa[tq][1], vb[1][tn], acc, 0, 0, 0);
                    #pragma unroll
                    for (int r = 0; r < 4; ++r) {
                        const int row = 16 * tq + 4 * g + r;
                        if (row < NG_)
                            out[(size_t)wb * (NG_ * NC_) + (size_t)row * NC_ + 32 * h + 16 * tn + l15] = acc[r];
                    }
                }
        }
    } else {
        // ======================= global path (unchanged) =======================
        GlobShared& S = sm.g;
        const int img = blk;

        if (t < NC_) S.xavgS[t] = xavg[img * NC_ + t];
        __syncthreads();

        if (t < NC_) {
            const int h = t >> 5, jj = t & 31;
            float acc = bq[h * DH_ + jj];
            for (int c = 0; c < NC_; ++c) acc += S.xavgS[c] * Wq[c * NC_ + h * DH_ + jj];
            S.qa[h][jj] = acc;
        }
        __syncthreads();

        if (t < NC_) {
            const int c = t;
            #pragma unroll
            for (int h = 0; h < NH_; ++h) {
                float acc = 0.f;
                const float* wr = Wkv + (size_t)c * (2 * NC_) + h * DH_;
                #pragma unroll
                for (int jj = 0; jj < DH_; ++jj) acc += wr[jj] * S.qa[h][jj];
                S.u[h][c] = acc;
            }
        } else if (t < NC_ + NH_) {
            const int h = t - NC_;
            float acc = 0.f;
            for (int jj = 0; jj < DH_; ++jj) acc += S.qa[h][jj] * bkv[h * DH_ + jj];
            S.cst[h] = acc;
        }
        __syncthreads();

        float lmax0 = -1e30f, lmax1 = -1e30f, lmax2 = -1e30f, lmax3 = -1e30f;
        for (int m = t; m < NT_; m += 256) {
            const float* xr = xtotal + (size_t)(img * NT_ + m) * NC_;
            float a0 = S.cst[0], a1 = S.cst[1], a2 = S.cst[2], a3 = S.cst[3];
            for (int c = 0; c < NC_; ++c) {
                float xv = xr[c];
                a0 += xv * S.u[0][c];
                a1 += xv * S.u[1][c];
                a2 += xv * S.u[2][c];
                a3 += xv * S.u[3][c];
            }
            S.s[m][0] = a0; S.s[m][1] = a1; S.s[m][2] = a2; S.s[m][3] = a3;
            lmax0 = fmaxf(lmax0, a0); lmax1 = fmaxf(lmax1, a1);
            lmax2 = fmaxf(lmax2, a2); lmax3 = fmaxf(lmax3, a3);
        }
        float lm[NH_] = {lmax0, lmax1, lmax2, lmax3};
        for (int h = 0; h < NH_; ++h) {
            __syncthreads();
            S.red[t] = lm[h];
            __syncthreads();
            for (int off = 128; off > 0; off >>= 1) {
                if (t < off) S.red[t] = fmaxf(S.red[t], S.red[t + off]);
                __syncthreads();
            }
            if (t == 0) S.smax[h] = S.red[0];
        }
        __syncthreads();

        float ls[NH_] = {0.f, 0.f, 0.f, 0.f};
        for (int m = t; m < NT_; m += 256) {
            #pragma unroll
            for (int h = 0; h < NH_; ++h) {
                float e = __expf(S.s[m][h] - S.smax[h]);
                S.s[m][h] = e;
                ls[h] += e;
            }
        }
        for (int h = 0; h < NH_; ++h) {
            __syncthreads();
            S.red[t] = ls[h];
            __syncthreads();
            for (int off = 128; off > 0; off >>= 1) {
                if (t < off) S.red[t] += S.red[t + off];
                __syncthreads();
            }
            if (t == 0) S.ssum[h] = S.red[0];
        }
        __syncthreads();

        {
            const int c = t & 127, half = t >> 7;
            float a0 = 0.f, a1 = 0.f, a2 = 0.f, a3 = 0.f;
            const int m0 = half * (NT_ / 2), m1 = m0 + NT_ / 2;
            for (int m = m0; m < m1; ++m) {
                float xv = xtotal[(size_t)(img * NT_ + m) * NC_ + c];
                a0 += S.s[m][0] * xv; a1 += S.s[m][1] * xv;
                a2 += S.s[m][2] * xv; a3 += S.s[m][3] * xv;
            }
            S.wpart[half][0][c] = a0; S.wpart[half][1][c] = a1;
            S.wpart[half][2][c] = a2; S.wpart[half][3][c] = a3;
        }
        __syncthreads();

        if (t < NC_) {
            const int h = t >> 5;
            const float winv = 1.f / S.ssum[h];
            float acc = bkv[NC_ + t];
            for (int c = 0; c < NC_; ++c) {
                float wv = (S.wpart[0][h][c] + S.wpart[1][h][c]) * winv;
                acc += wv * Wkv[(size_t)c * (2 * NC_) + NC_ + t];
            }
            out[(size_t)NB_ * (NG_ * NC_) + img * NC_ + t] = acc;
        }
    }
}

extern "C" void kernel_launch(void* const* d_in, const int* in_sizes, int n_in,
                              void* d_out, int out_size, void* d_ws, size_t ws_size,
                              hipStream_t stream) {
    const float* x      = (const float*)d_in[0];
    const float* xtotal = (const float*)d_in[1];
    const float* xavg   = (const float*)d_in[2];
    const float* mask   = (const float*)d_in[3];
    const float* Wq     = (const float*)d_in[4];
    const float* bq     = (const float*)d_in[5];
    const float* Wkv    = (const float*)d_in[6];
    const float* bkv    = (const float*)d_in[7];
    const float* btab   = (const float*)d_in[8];
    const int*   ridx   = (const int*)d_in[9];
    float* outp = (float*)d_out;
    u16*   ws   = (u16*)d_ws;
    (void)in_sizes; (void)n_in; (void)out_size; (void)ws_size;

    // prep: 24 weight-frag blocks + 1024 bias-table blocks
    prep_kernel<<<24 + 1024, 256, 0, stream>>>(Wq, Wkv, btab, ridx, mask, ws);
    // global blocks first (long pole ~15us, overlaps the window wave)
    wa2_kernel<<<NB_ + NIMG, 256, 0, stream>>>(x, xtotal, xavg, Wq, bq,
                                               Wkv, bkv, outp, (const u16*)ws);
}